// Round 1
// baseline (300.917 us; speedup 1.0000x reference)
//
#include <hip/hip_runtime.h>
#include <hip/hip_fp16.h>
#include <stdint.h>

#define NB     256     // batch
#define NI     1152    // input capsules
#define DI     8       // input capsule dim
#define NO     10      // output capsules
#define NK     16      // output capsule dim
#define NCHUNK 18      // NI / 64
#define XPAD   9       // padded x row stride (bank-conflict-free: gcd(9,32)=1)
#define NTHR   640     // 10 waves; wave w handles output capsule o = w

// u_hat[i,o,:] = W[i,o,:,:] @ x[i,:]
__device__ __forceinline__ void compute_uhat(int i, int o,
        const float* x_lds, const float* __restrict__ W, float* u)
{
    float xr[DI];
#pragma unroll
    for (int d = 0; d < DI; ++d) xr[d] = x_lds[i * XPAD + d];
    const float4* wp = reinterpret_cast<const float4*>(
        W + (size_t)(i * NO + o) * (NK * DI));
#pragma unroll
    for (int k = 0; k < NK; ++k) {
        float4 w0 = wp[2 * k];
        float4 w1 = wp[2 * k + 1];
        u[k] = w0.x * xr[0] + w0.y * xr[1] + w0.z * xr[2] + w0.w * xr[3] +
               w1.x * xr[4] + w1.y * xr[5] + w1.z * xr[6] + w1.w * xr[7];
    }
}

template <bool USE_WS>
__global__ __launch_bounds__(NTHR)
void digitcaps_kernel(const float* __restrict__ x,
                      const float* __restrict__ W,
                      const float* __restrict__ bias,
                      float* __restrict__ out,
                      uint32_t* __restrict__ uws)
{
    __shared__ float x_lds[NI * XPAD];        // ~41.5 KB
    __shared__ float blog_lds[64][NO + 1];    // pad 11: 2-way aliasing only
    __shared__ float v_lds[NO][NK];

    const int b   = blockIdx.x;
    const int tid = threadIdx.x;
    const int o   = tid >> 6;   // 0..9 (wave index)
    const int il  = tid & 63;   // lane = i_local

    // stage x[b] (9216 floats), coalesced in, padded rows in LDS
    const float* xb = x + (size_t)b * (NI * DI);
    for (int idx = tid; idx < NI * DI; idx += NTHR)
        x_lds[(idx >> 3) * XPAD + (idx & 7)] = xb[idx];

    float bias_r[NK];
#pragma unroll
    for (int k = 0; k < NK; ++k) bias_r[k] = bias[o * NK + k];

    __syncthreads();

    float blog[NCHUNK];   // b_logits for this thread's (i,o) pairs, in registers
    float s_acc[NK];

    // wave-reduce s_acc over 64 lanes, add bias, squash, publish v
    auto finish_iter = [&](int it) {
#pragma unroll
        for (int off = 32; off >= 1; off >>= 1) {
#pragma unroll
            for (int k = 0; k < NK; ++k)
                s_acc[k] += __shfl_xor(s_acc[k], off, 64);
        }
        float sv[NK];
        float sq = 0.f;
#pragma unroll
        for (int k = 0; k < NK; ++k) { sv[k] = s_acc[k] + bias_r[k]; sq += sv[k] * sv[k]; }
        const float scale = sq / (1.f + sq) / sqrtf(sq + 1e-9f);  // matches reference squash
        if (il == 0) {
            if (it == 2) {
#pragma unroll
                for (int k = 0; k < NK; ++k)
                    out[(size_t)b * (NO * NK) + o * NK + k] = scale * sv[k];
            } else {
#pragma unroll
                for (int k = 0; k < NK; ++k)
                    v_lds[o][k] = scale * sv[k];
            }
        }
    };

    // ---------------- iteration 0: c = softmax(0) = 0.1 exactly ----------------
#pragma unroll
    for (int k = 0; k < NK; ++k) s_acc[k] = 0.f;

#pragma unroll
    for (int c = 0; c < NCHUNK; ++c) {
        const int i = c * 64 + il;
        float u[NK];
        compute_uhat(i, o, x_lds, W, u);
        if (USE_WS) {
            // cache u_hat as fp16, layout [b][c][o][il][k] -> wave writes 2KB contiguous
            uint32_t pk[8];
#pragma unroll
            for (int k2 = 0; k2 < 8; ++k2) {
                union { __half2 h; uint32_t w; } cv;
                cv.h = __float22half2_rn(make_float2(u[2 * k2], u[2 * k2 + 1]));
                pk[k2] = cv.w;
            }
            const size_t base = ((((size_t)b * NCHUNK + c) * NO + o) * 64 + il) * 8;
            uint4* dst = reinterpret_cast<uint4*>(uws + base);
            dst[0] = make_uint4(pk[0], pk[1], pk[2], pk[3]);
            dst[1] = make_uint4(pk[4], pk[5], pk[6], pk[7]);
        }
#pragma unroll
        for (int k = 0; k < NK; ++k) s_acc[k] += u[k];
        blog[c] = 0.f;
    }
#pragma unroll
    for (int k = 0; k < NK; ++k) s_acc[k] *= 0.1f;

    finish_iter(0);
    __syncthreads();

    // ---------------- iterations 1, 2: fused agreement + softmax + s ----------------
#pragma unroll
    for (int it = 1; it <= 2; ++it) {
#pragma unroll
        for (int k = 0; k < NK; ++k) s_acc[k] = 0.f;

#pragma unroll
        for (int c = 0; c < NCHUNK; ++c) {
            const int i = c * 64 + il;
            float u[NK];
            if (USE_WS) {
                const size_t base = ((((size_t)b * NCHUNK + c) * NO + o) * 64 + il) * 8;
                const uint4* src = reinterpret_cast<const uint4*>(uws + base);
                uint4 p0 = src[0], p1 = src[1];
                uint32_t pk[8] = {p0.x, p0.y, p0.z, p0.w, p1.x, p1.y, p1.z, p1.w};
#pragma unroll
                for (int k2 = 0; k2 < 8; ++k2) {
                    union { uint32_t w; __half2 h; } cv; cv.w = pk[k2];
                    float2 f = __half22float2(cv.h);
                    u[2 * k2] = f.x; u[2 * k2 + 1] = f.y;
                }
            } else {
                compute_uhat(i, o, x_lds, W, u);
            }

            // agreement with previous v, update logit (register-resident)
            float a = 0.f;
#pragma unroll
            for (int k = 0; k < NK; ++k) a += v_lds[o][k] * u[k];  // broadcast reads: free
            blog[c] += a;

            // softmax over the 10 output capsules for this i (exchange via LDS)
            __syncthreads();                 // previous chunk's softmax reads done
            blog_lds[il][o] = blog[c];
            __syncthreads();
            float m = blog_lds[il][0];
#pragma unroll
            for (int oo = 1; oo < NO; ++oo) m = fmaxf(m, blog_lds[il][oo]);
            float den = 0.f;
#pragma unroll
            for (int oo = 0; oo < NO; ++oo) den += __expf(blog_lds[il][oo] - m);
            const float cv = __expf(blog[c] - m) / den;

#pragma unroll
            for (int k = 0; k < NK; ++k) s_acc[k] += cv * u[k];
        }
        finish_iter(it);
        __syncthreads();
    }
}

extern "C" void kernel_launch(void* const* d_in, const int* in_sizes, int n_in,
                              void* d_out, int out_size, void* d_ws, size_t ws_size,
                              hipStream_t stream)
{
    const float* x    = (const float*)d_in[0];  // [256,1152,8]
    const float* W    = (const float*)d_in[1];  // [1152,10,16,8]
    const float* bias = (const float*)d_in[2];  // [10,16]
    float* out = (float*)d_out;                 // [256,10,16]

    const size_t need = (size_t)NB * NI * NO * NK * sizeof(__half);  // 94.4 MB
    if (ws_size >= need) {
        digitcaps_kernel<true><<<NB, NTHR, 0, stream>>>(x, W, bias, out, (uint32_t*)d_ws);
    } else {
        digitcaps_kernel<false><<<NB, NTHR, 0, stream>>>(x, W, bias, out, nullptr);
    }
}

// Round 2
// 242.751 us; speedup vs baseline: 1.2396x; 1.2396x over previous
//
#include <hip/hip_runtime.h>
#include <hip/hip_fp16.h>
#include <stdint.h>

#define NB     256     // batch
#define NI     1152    // input capsules
#define DI     8       // input capsule dim
#define NO     10      // output capsules
#define NK     16      // output capsule dim
#define NCHUNK 18      // NI / 64  (kernel B chunking)
#define XPAD   9

// ws layout (uint32 units):
//   [0 .. 23592959]  u_hat fp16, layout [b][c18][o][il64][k16]  (92160 u32 per b)
//   [23592960 .. ]   s0 fp32 [b][o][k]  (40960 floats = 163840 B)
#define UHAT_U32_PER_B 92160u
#define S0_OFF_U32     23592960u
#define WS_NEED_BYTES  (94371840ull + 163840ull)

// ---------------------------------------------------------------------------
// Kernel A: u_hat = einsum('bid,iokd->biok'), fp16 to ws; also s0 = 0.1*sum_i u
// grid (36 c-chunks of 32 i's, 16 b-tiles of 16 b's), 320 threads = (o, il32)
// ---------------------------------------------------------------------------
__global__ __launch_bounds__(320)
void uhat_kernel(const float* __restrict__ x, const float* __restrict__ W,
                 uint32_t* __restrict__ ws)
{
    __shared__ float x_lds[16 * 32 * XPAD];   // [bb][il][d], pad 9 -> 18.4 KB

    const int c   = blockIdx.x;          // 0..35
    const int b0  = blockIdx.y * 16;     // b-tile base
    const int tid = threadIdx.x;
    const int o   = tid >> 5;            // 0..9
    const int il  = tid & 31;            // 0..31

    // stage x[b0..b0+15][c*32 .. c*32+31][0..7], coalesced
    for (int idx = tid; idx < 16 * 256; idx += 320) {
        const int bb = idx >> 8, r = idx & 255;
        x_lds[bb * (32 * XPAD) + (r >> 3) * XPAD + (r & 7)] =
            x[(size_t)(b0 + bb) * (NI * DI) + c * 256 + r];
    }
    __syncthreads();

    const int i = c * 32 + il;
    const float4* wp = reinterpret_cast<const float4*>(W + ((size_t)i * NO + o) * (NK * DI));
    float* s0f = reinterpret_cast<float*>(ws + S0_OFF_U32);

    const int cB   = i >> 6;    // kernel-B chunk
    const int il64 = i & 63;

#pragma unroll
    for (int h = 0; h < 2; ++h) {          // k-halves: k = h*8 + kk
        float4 wr[16];
#pragma unroll
        for (int t = 0; t < 16; ++t) wr[t] = wp[h * 16 + t];

        for (int bb = 0; bb < 16; ++bb) {
            float xr[DI];
#pragma unroll
            for (int d = 0; d < DI; ++d) xr[d] = x_lds[bb * (32 * XPAD) + il * XPAD + d];

            float u[8];
#pragma unroll
            for (int kk = 0; kk < 8; ++kk) {
                const float4 w0 = wr[2 * kk], w1 = wr[2 * kk + 1];
                u[kk] = w0.x * xr[0] + w0.y * xr[1] + w0.z * xr[2] + w0.w * xr[3] +
                        w1.x * xr[4] + w1.y * xr[5] + w1.z * xr[6] + w1.w * xr[7];
            }

            // pack fp16, coalesced store (wave writes two 512B segments)
            uint32_t pk[4];
#pragma unroll
            for (int t = 0; t < 4; ++t) {
                union { __half2 h2; uint32_t w; } cv;
                cv.h2 = __float22half2_rn(make_float2(u[2 * t], u[2 * t + 1]));
                pk[t] = cv.w;
            }
            const int b = b0 + bb;
            const size_t base = ((((size_t)b * NCHUNK + cB) * NO + o) * 64 + il64) * 8 + h * 4;
            *reinterpret_cast<uint4*>(ws + base) = make_uint4(pk[0], pk[1], pk[2], pk[3]);

            // s0 partial: reduce u over the 32 i-lanes, one atomicAdd per (b,o,k)
            float r8[8];
#pragma unroll
            for (int kk = 0; kk < 8; ++kk) r8[kk] = u[kk];
#pragma unroll
            for (int m = 16; m >= 1; m >>= 1)
#pragma unroll
                for (int kk = 0; kk < 8; ++kk) r8[kk] += __shfl_xor(r8[kk], m, 64);
            if (il == 0) {
#pragma unroll
                for (int kk = 0; kk < 8; ++kk)
                    atomicAdd(&s0f[(size_t)b * (NO * NK) + o * NK + h * 8 + kk], 0.1f * r8[kk]);
            }
        }
    }
}

// ---------------------------------------------------------------------------
// Kernel B: routing iterations. grid 256 (one block per b), 640 thr = (o, il64)
// ---------------------------------------------------------------------------
__global__ __launch_bounds__(640)
void route_kernel(const float* __restrict__ bias, float* __restrict__ out,
                  const uint32_t* __restrict__ ws)
{
    __shared__ float blog_lds[NI * 11];   // pad 11 -> conflict-light, 50.7 KB
    __shared__ float v_lds[NO][NK];

    const int b   = blockIdx.x;
    const int tid = threadIdx.x;
    const int o   = tid >> 6;
    const int il  = tid & 63;

    float bias_r[NK];
#pragma unroll
    for (int k = 0; k < NK; ++k) bias_r[k] = bias[o * NK + k];

    // ---- prologue: v0 = squash(s0 + bias) ----
    if (il < NK) {
        const float* s0f = reinterpret_cast<const float*>(ws + S0_OFF_U32);
        const float sv = s0f[(size_t)b * (NO * NK) + o * NK + il] + bias_r[il];
        float sq = sv * sv;
#pragma unroll
        for (int m = 8; m >= 1; m >>= 1) sq += __shfl_xor(sq, m, 64);
        const float scale = sq / (1.f + sq) / sqrtf(sq + 1e-9f);
        v_lds[o][il] = scale * sv;
    }
    __syncthreads();

    float blog[NCHUNK];
#pragma unroll
    for (int c = 0; c < NCHUNK; ++c) blog[c] = 0.f;

    const uint32_t* ub = ws + (size_t)b * UHAT_U32_PER_B + o * 512 + il * 8;

    float s_acc[NK];
#pragma unroll
    for (int it = 0; it < 2; ++it) {
#pragma unroll
        for (int k = 0; k < NK; ++k) s_acc[k] = 0.f;

        // prefetch chunk 0
        uint4 p0 = *reinterpret_cast<const uint4*>(ub);
        uint4 p1 = *reinterpret_cast<const uint4*>(ub + 4);

        for (int c = 0; c < NCHUNK; ++c) {
            float u[NK];
            {
                const uint32_t pk[8] = {p0.x, p0.y, p0.z, p0.w, p1.x, p1.y, p1.z, p1.w};
#pragma unroll
                for (int t = 0; t < 8; ++t) {
                    union { uint32_t w; __half2 h2; } cv; cv.w = pk[t];
                    const float2 f = __half22float2(cv.h2);
                    u[2 * t] = f.x; u[2 * t + 1] = f.y;
                }
            }
            if (c < NCHUNK - 1) {   // prefetch next chunk; hides under barrier+softmax
                p0 = *reinterpret_cast<const uint4*>(ub + (size_t)(c + 1) * 5120);
                p1 = *reinterpret_cast<const uint4*>(ub + (size_t)(c + 1) * 5120 + 4);
            }

            float a = 0.f;
#pragma unroll
            for (int k = 0; k < NK; ++k) a += v_lds[o][k] * u[k];
            blog[c] += a;

            const int i = c * 64 + il;
            blog_lds[i * 11 + o] = blog[c];
            __syncthreads();

            float m = blog_lds[i * 11 + 0];
#pragma unroll
            for (int oo = 1; oo < NO; ++oo) m = fmaxf(m, blog_lds[i * 11 + oo]);
            float den = 0.f;
#pragma unroll
            for (int oo = 0; oo < NO; ++oo) den += __expf(blog_lds[i * 11 + oo] - m);
            const float cv = __expf(blog[c] - m) / den;

#pragma unroll
            for (int k = 0; k < NK; ++k) s_acc[k] += cv * u[k];
        }

        // finish: reduce s over i-lanes, squash, publish
#pragma unroll
        for (int off = 32; off >= 1; off >>= 1)
#pragma unroll
            for (int k = 0; k < NK; ++k) s_acc[k] += __shfl_xor(s_acc[k], off, 64);

        float sv[NK], sq = 0.f;
#pragma unroll
        for (int k = 0; k < NK; ++k) { sv[k] = s_acc[k] + bias_r[k]; sq += sv[k] * sv[k]; }
        const float scale = sq / (1.f + sq) / sqrtf(sq + 1e-9f);
        if (il == 0) {
            if (it == 1) {
#pragma unroll
                for (int k = 0; k < NK; ++k)
                    out[(size_t)b * (NO * NK) + o * NK + k] = scale * sv[k];
            } else {
#pragma unroll
                for (int k = 0; k < NK; ++k) v_lds[o][k] = scale * sv[k];
            }
        }
        __syncthreads();
    }
}

// ---------------------------------------------------------------------------
// Fallback (ws too small): round-1 monolithic kernel, recompute u_hat per pass
// ---------------------------------------------------------------------------
__device__ __forceinline__ void compute_uhat_fb(int i, int o,
        const float* x_lds, const float* __restrict__ W, float* u)
{
    float xr[DI];
#pragma unroll
    for (int d = 0; d < DI; ++d) xr[d] = x_lds[i * XPAD + d];
    const float4* wp = reinterpret_cast<const float4*>(W + (size_t)(i * NO + o) * (NK * DI));
#pragma unroll
    for (int k = 0; k < NK; ++k) {
        float4 w0 = wp[2 * k], w1 = wp[2 * k + 1];
        u[k] = w0.x * xr[0] + w0.y * xr[1] + w0.z * xr[2] + w0.w * xr[3] +
               w1.x * xr[4] + w1.y * xr[5] + w1.z * xr[6] + w1.w * xr[7];
    }
}

__global__ __launch_bounds__(640)
void digitcaps_fallback(const float* __restrict__ x, const float* __restrict__ W,
                        const float* __restrict__ bias, float* __restrict__ out)
{
    __shared__ float x_lds[NI * XPAD];
    __shared__ float blog_lds[64][NO + 1];
    __shared__ float v_lds[NO][NK];
    const int b = blockIdx.x, tid = threadIdx.x;
    const int o = tid >> 6, il = tid & 63;
    const float* xb = x + (size_t)b * (NI * DI);
    for (int idx = tid; idx < NI * DI; idx += 640)
        x_lds[(idx >> 3) * XPAD + (idx & 7)] = xb[idx];
    float bias_r[NK];
#pragma unroll
    for (int k = 0; k < NK; ++k) bias_r[k] = bias[o * NK + k];
    __syncthreads();
    float blog[NCHUNK], s_acc[NK];
    auto finish = [&](int it) {
#pragma unroll
        for (int off = 32; off >= 1; off >>= 1)
#pragma unroll
            for (int k = 0; k < NK; ++k) s_acc[k] += __shfl_xor(s_acc[k], off, 64);
        float sv[NK], sq = 0.f;
#pragma unroll
        for (int k = 0; k < NK; ++k) { sv[k] = s_acc[k] + bias_r[k]; sq += sv[k] * sv[k]; }
        const float scale = sq / (1.f + sq) / sqrtf(sq + 1e-9f);
        if (il == 0) {
            if (it == 2) {
#pragma unroll
                for (int k = 0; k < NK; ++k) out[(size_t)b * 160 + o * NK + k] = scale * sv[k];
            } else {
#pragma unroll
                for (int k = 0; k < NK; ++k) v_lds[o][k] = scale * sv[k];
            }
        }
    };
#pragma unroll
    for (int k = 0; k < NK; ++k) s_acc[k] = 0.f;
    for (int c = 0; c < NCHUNK; ++c) {
        float u[NK];
        compute_uhat_fb(c * 64 + il, o, x_lds, W, u);
#pragma unroll
        for (int k = 0; k < NK; ++k) s_acc[k] += u[k];
        blog[c] = 0.f;
    }
#pragma unroll
    for (int k = 0; k < NK; ++k) s_acc[k] *= 0.1f;
    finish(0);
    __syncthreads();
    for (int it = 1; it <= 2; ++it) {
#pragma unroll
        for (int k = 0; k < NK; ++k) s_acc[k] = 0.f;
        for (int c = 0; c < NCHUNK; ++c) {
            const int i = c * 64 + il;
            float u[NK];
            compute_uhat_fb(i, o, x_lds, W, u);
            float a = 0.f;
#pragma unroll
            for (int k = 0; k < NK; ++k) a += v_lds[o][k] * u[k];
            blog[c] += a;
            __syncthreads();
            blog_lds[il][o] = blog[c];
            __syncthreads();
            float m = blog_lds[il][0];
#pragma unroll
            for (int oo = 1; oo < NO; ++oo) m = fmaxf(m, blog_lds[il][oo]);
            float den = 0.f;
#pragma unroll
            for (int oo = 0; oo < NO; ++oo) den += __expf(blog_lds[il][oo] - m);
            const float cv = __expf(blog[c] - m) / den;
#pragma unroll
            for (int k = 0; k < NK; ++k) s_acc[k] += cv * u[k];
        }
        finish(it);
        __syncthreads();
    }
}

extern "C" void kernel_launch(void* const* d_in, const int* in_sizes, int n_in,
                              void* d_out, int out_size, void* d_ws, size_t ws_size,
                              hipStream_t stream)
{
    const float* x    = (const float*)d_in[0];  // [256,1152,8]
    const float* W    = (const float*)d_in[1];  // [1152,10,16,8]
    const float* bias = (const float*)d_in[2];  // [10,16]
    float* out = (float*)d_out;                 // [256,10,16]

    if (ws_size >= WS_NEED_BYTES) {
        // zero the s0 accumulator region (ws is poisoned before every launch)
        hipMemsetAsync((char*)d_ws + (size_t)S0_OFF_U32 * 4, 0, NB * NO * NK * 4, stream);
        uhat_kernel<<<dim3(36, 16), 320, 0, stream>>>(x, W, (uint32_t*)d_ws);
        route_kernel<<<NB, 640, 0, stream>>>(bias, out, (const uint32_t*)d_ws);
    } else {
        digitcaps_fallback<<<NB, 640, 0, stream>>>(x, W, bias, out);
    }
}